// Round 3
// baseline (624.536 us; speedup 1.0000x reference)
//
#include <hip/hip_runtime.h>
#include <hip/hip_bf16.h>
#include <hip/hip_fp16.h>
#include <math.h>

#define D_DIM 512
#define LX 2048
#define LY 2048
#define NB 8

typedef float f32x4 __attribute__((ext_vector_type(4)));
typedef __bf16 bf16x8 __attribute__((ext_vector_type(8)));

__device__ __forceinline__ unsigned short f2bf_rn(float f) {
    unsigned u = __float_as_uint(f);
    unsigned r = (u + 0x7fffu + ((u >> 16) & 1u)) >> 16;
    return (unsigned short)r;
}
__device__ __forceinline__ float bf2f(unsigned short h) {
    return __uint_as_float(((unsigned)h) << 16);
}
__device__ __forceinline__ void async16(void* lds, const void* g) {
    __builtin_amdgcn_global_load_lds(
        (const __attribute__((address_space(1))) void*)g,
        (__attribute__((address_space(3))) void*)lds, 16, 0, 0);
}
__device__ __forceinline__ bf16x8 ldfrag(const char* p) {
    return *(const bf16x8*)p;
}

// ---------------------------------------------------------------------------
// k0a: row-major fp32 [R][512] -> frag-order hi/lo bf16.
// ---------------------------------------------------------------------------
__global__ __launch_bounds__(256) void repack_hilo_k(
    const float* __restrict__ src, unsigned short* __restrict__ dh,
    unsigned short* __restrict__ dl, int nfb)
{
    int fbid = blockIdx.x * 4 + (threadIdx.x >> 6);
    if (fbid >= nfb) return;
    int lane = threadIdx.x & 63;
    int r16 = fbid >> 4, k32 = fbid & 15;
    int row = r16 * 16 + (lane & 15);
    int col = k32 * 32 + (lane >> 4) * 8;
    const float* s = src + (size_t)row * D_DIM + col;
    float4 v0 = *(const float4*)s;
    float4 v1 = *(const float4*)(s + 4);
    float vv[8] = {v0.x, v0.y, v0.z, v0.w, v1.x, v1.y, v1.z, v1.w};
    unsigned hh[4], ll[4];
    #pragma unroll
    for (int k = 0; k < 4; ++k) {
        unsigned short ha = f2bf_rn(vv[2*k]),   hb = f2bf_rn(vv[2*k+1]);
        unsigned short la = f2bf_rn(vv[2*k]   - bf2f(ha));
        unsigned short lb = f2bf_rn(vv[2*k+1] - bf2f(hb));
        hh[k] = (unsigned)ha | ((unsigned)hb << 16);
        ll[k] = (unsigned)la | ((unsigned)lb << 16);
    }
    size_t off = (size_t)fbid * 512 + lane * 8;
    *(uint4*)(dh + off) = make_uint4(hh[0], hh[1], hh[2], hh[3]);
    *(uint4*)(dl + off) = make_uint4(ll[0], ll[1], ll[2], ll[3]);
}

// ---------------------------------------------------------------------------
// k0d: x[b][c][dd] fp32 -> xtf bf16 frag-order of x^T (rows=dd, k=c)
// ---------------------------------------------------------------------------
__global__ __launch_bounds__(256) void xt_repack_k(
    const float* __restrict__ x, unsigned short* __restrict__ xtf)
{
    __shared__ unsigned short T2[64][72];
    int ct = blockIdx.x, dt = blockIdx.y, b = blockIdx.z;
    int tid = threadIdx.x;
    const float* xb = x + (size_t)b * LX * D_DIM;
    int rc = tid >> 4;
    int d4 = (tid & 15) * 4;
    #pragma unroll
    for (int i = 0; i < 4; ++i) {
        int cl = rc + i * 16;
        float4 v = *(const float4*)(xb + (size_t)(ct * 64 + cl) * D_DIM + dt * 64 + d4);
        T2[d4 + 0][cl] = f2bf_rn(v.x);
        T2[d4 + 1][cl] = f2bf_rn(v.y);
        T2[d4 + 2][cl] = f2bf_rn(v.z);
        T2[d4 + 3][cl] = f2bf_rn(v.w);
    }
    __syncthreads();
    #pragma unroll
    for (int si = 0; si < 2; ++si) {
        int s = tid + si * 256;
        int fb = s >> 6, lane = s & 63;
        int dd16l = fb >> 1, c32l = fb & 1;
        int ddl = dd16l * 16 + (lane & 15);
        int cl  = c32l * 32 + (lane >> 4) * 8;
        uint4 v = *(const uint4*)&T2[ddl][cl];
        size_t off = ((size_t)((b * 32 + dt * 4 + dd16l) * 64 + (ct * 2 + c32l)) * 64 + lane) * 8;
        *(uint4*)(xtf + off) = v;
    }
}

// ---------------------------------------------------------------------------
// k1: xw = x @ Wb^T via 3-term hi/lo MFMA (hh, hl, lh). Emits frag-order hi/lo.
// ---------------------------------------------------------------------------
__global__ __launch_bounds__(256, 2) void xw_mfma_k(
    const unsigned short* __restrict__ xfh, const unsigned short* __restrict__ xfl,
    const unsigned short* __restrict__ wfh, const unsigned short* __restrict__ wfl,
    unsigned short* __restrict__ xwfh, unsigned short* __restrict__ xwfl)
{
    __shared__ char smem[49152];
    const int tid = threadIdx.x, lane = tid & 63, w = tid >> 6;
    const int Mt = blockIdx.x, Nt = blockIdx.y;
    f32x4 acc[2][4];
    #pragma unroll
    for (int m = 0; m < 2; ++m)
        #pragma unroll
        for (int n = 0; n < 4; ++n) acc[m][n] = (f32x4){0.f, 0.f, 0.f, 0.f};

    for (int kc = 0; kc < 8; ++kc) {
        __syncthreads();
        #pragma unroll
        for (int i = 0; i < 8; ++i) {
            int seg = w + 4 * i;
            int h = seg >> 4, c16l = (seg >> 1) & 7, k32l = seg & 1;
            size_t fb = (size_t)(Mt * 8 + c16l) * 16 + kc * 2 + k32l;
            const unsigned short* src = (h ? xfl : xfh) + fb * 512 + lane * 8;
            char* dst = smem + (h ? 16384 : 0) + ((c16l * 2 + k32l) * 64 + lane) * 16;
            async16(dst, src);
        }
        #pragma unroll
        for (int i = 0; i < 4; ++i) {
            int seg = w + 4 * i;
            int h = seg >> 3, n16l = (seg >> 1) & 3, k32l = seg & 1;
            size_t fb = (size_t)(Nt * 4 + n16l) * 16 + kc * 2 + k32l;
            const unsigned short* src = (h ? wfl : wfh) + fb * 512 + lane * 8;
            char* dst = smem + (h ? 40960 : 32768) + ((n16l * 2 + k32l) * 64 + lane) * 16;
            async16(dst, src);
        }
        __syncthreads();
        #pragma unroll
        for (int ks = 0; ks < 2; ++ks) {
            bf16x8 ah[2], al[2], bh[4], bl[4];
            #pragma unroll
            for (int m = 0; m < 2; ++m) {
                int c16l = w * 2 + m;
                ah[m] = ldfrag(smem +     0 + ((c16l * 2 + ks) * 64 + lane) * 16);
                al[m] = ldfrag(smem + 16384 + ((c16l * 2 + ks) * 64 + lane) * 16);
            }
            #pragma unroll
            for (int n = 0; n < 4; ++n) {
                bh[n] = ldfrag(smem + 32768 + ((n * 2 + ks) * 64 + lane) * 16);
                bl[n] = ldfrag(smem + 40960 + ((n * 2 + ks) * 64 + lane) * 16);
            }
            #pragma unroll
            for (int m = 0; m < 2; ++m)
                #pragma unroll
                for (int n = 0; n < 4; ++n) {
                    acc[m][n] = __builtin_amdgcn_mfma_f32_16x16x32_bf16(ah[m], bh[n], acc[m][n], 0, 0, 0);
                    acc[m][n] = __builtin_amdgcn_mfma_f32_16x16x32_bf16(ah[m], bl[n], acc[m][n], 0, 0, 0);
                    acc[m][n] = __builtin_amdgcn_mfma_f32_16x16x32_bf16(al[m], bh[n], acc[m][n], 0, 0, 0);
                }
        }
    }
    __syncthreads();
    float* E = (float*)smem;
    const int q = lane >> 4, c15 = lane & 15;
    #pragma unroll
    for (int m = 0; m < 2; ++m)
        #pragma unroll
        for (int n = 0; n < 4; ++n)
            #pragma unroll
            for (int r = 0; r < 4; ++r)
                E[(w * 32 + m * 16 + q * 4 + r) * 68 + n * 16 + c15] = acc[m][n][r];
    __syncthreads();
    #pragma unroll
    for (int i = 0; i < 4; ++i) {
        int s = tid + i * 256;
        int c16l = s >> 7, e32l = (s >> 6) & 1, lp = s & 63;
        int row = c16l * 16 + (lp & 15), col = e32l * 32 + (lp >> 4) * 8;
        const float* sp = E + row * 68 + col;
        unsigned hh[4], ll[4];
        #pragma unroll
        for (int k = 0; k < 4; ++k) {
            float a = sp[2 * k], bq = sp[2 * k + 1];
            unsigned short ha = f2bf_rn(a), hb = f2bf_rn(bq);
            unsigned short la = f2bf_rn(a - bf2f(ha)), lb = f2bf_rn(bq - bf2f(hb));
            hh[k] = (unsigned)ha | ((unsigned)hb << 16);
            ll[k] = (unsigned)la | ((unsigned)lb << 16);
        }
        size_t fb = (size_t)(Mt * 8 + c16l) * 16 + (Nt * 2 + e32l);
        *(uint4*)(xwfh + fb * 512 + lp * 8) = make_uint4(hh[0], hh[1], hh[2], hh[3]);
        *(uint4*)(xwfl + fb * 512 + lp * 8) = make_uint4(ll[0], ll[1], ll[2], ll[3]);
    }
}

// ---------------------------------------------------------------------------
// k2: flash bilinear attention v2. Block: 32 j x 256 c, 4 waves, c-split=2.
// Wave S-tile 32j x 64c (n=4), K-chunk 32, 3-term hi/lo.
// LDS 45 KB: XWh 0, XWl 16K, Yh 32K, Yl 34K, Pf 36K (8KB, c-halved), red 44K.
// Xt staging (PV) aliases XW region (32 KB). Outputs fp16 partials + (m,l).
// ---------------------------------------------------------------------------
__global__ __launch_bounds__(256, 3) void flash2_k(
    const unsigned short* __restrict__ yfh, const unsigned short* __restrict__ yfl,
    const unsigned short* __restrict__ xwfh, const unsigned short* __restrict__ xwfl,
    const unsigned short* __restrict__ xtf,
    __half* __restrict__ part, float* __restrict__ mpart, float* __restrict__ lpart)
{
    __shared__ char smem[46080];
    const int tid = threadIdx.x, lane = tid & 63, w = tid >> 6;
    const int jt = blockIdx.x, sp = blockIdx.y, b = blockIdx.z;
    const int q = lane >> 4, c15 = lane & 15;
    unsigned short* Pf = (unsigned short*)(smem + 36864);
    float* red_max = (float*)(smem + 45056);
    float* red_sum = (float*)(smem + 45568);

    f32x4 o[2][8];
    #pragma unroll
    for (int m = 0; m < 2; ++m)
        #pragma unroll
        for (int n = 0; n < 8; ++n) o[m][n] = (f32x4){0.f, 0.f, 0.f, 0.f};
    float m_run[2][4], l_run[2][4];
    #pragma unroll
    for (int m = 0; m < 2; ++m)
        #pragma unroll
        for (int r = 0; r < 4; ++r) { m_run[m][r] = -INFINITY; l_run[m][r] = 0.f; }

    for (int xt = 0; xt < 4; ++xt) {
        f32x4 sa[2][4];
        #pragma unroll
        for (int m = 0; m < 2; ++m)
            #pragma unroll
            for (int n = 0; n < 4; ++n) sa[m][n] = (f32x4){0.f, 0.f, 0.f, 0.f};

        // ---- S phase: K=512 in 16 chunks of 32 ----
        for (int kc = 0; kc < 16; ++kc) {
            __syncthreads();
            #pragma unroll
            for (int i = 0; i < 8; ++i) {            // XW: 32 segs (16 c16 x hi/lo)
                int seg = w + 4 * i;
                int h = seg >> 4, c16l = seg & 15;
                size_t fb = ((size_t)(b * 128 + sp * 64 + xt * 16 + c16l)) * 16 + kc;
                const unsigned short* src = (h ? xwfl : xwfh) + fb * 512 + lane * 8;
                async16(smem + h * 16384 + (c16l * 64 + lane) * 16, src);
            }
            {                                        // Y: 4 segs, one per wave
                int h = w >> 1, j16l = w & 1;
                size_t fb = ((size_t)(b * 128 + jt * 2 + j16l)) * 16 + kc;
                const unsigned short* src = (h ? yfl : yfh) + fb * 512 + lane * 8;
                async16(smem + 32768 + h * 2048 + j16l * 1024 + lane * 16, src);
            }
            __syncthreads();
            bf16x8 ah[2], al[2];
            ah[0] = ldfrag(smem + 32768 + lane * 16);
            ah[1] = ldfrag(smem + 32768 + 1024 + lane * 16);
            al[0] = ldfrag(smem + 34816 + lane * 16);
            al[1] = ldfrag(smem + 34816 + 1024 + lane * 16);
            #pragma unroll
            for (int n = 0; n < 4; ++n) {
                int c16l = w * 4 + n;
                bf16x8 bh = ldfrag(smem + (c16l * 64 + lane) * 16);
                bf16x8 bl = ldfrag(smem + 16384 + (c16l * 64 + lane) * 16);
                #pragma unroll
                for (int m = 0; m < 2; ++m) {
                    sa[m][n] = __builtin_amdgcn_mfma_f32_16x16x32_bf16(ah[m], bh, sa[m][n], 0, 0, 0);
                    sa[m][n] = __builtin_amdgcn_mfma_f32_16x16x32_bf16(ah[m], bl, sa[m][n], 0, 0, 0);
                    sa[m][n] = __builtin_amdgcn_mfma_f32_16x16x32_bf16(al[m], bh, sa[m][n], 0, 0, 0);
                }
            }
        }

        // ---- online softmax ----
        float pmax[2][4];
        #pragma unroll
        for (int m = 0; m < 2; ++m)
            #pragma unroll
            for (int r = 0; r < 4; ++r)
                pmax[m][r] = fmaxf(fmaxf(sa[m][0][r], sa[m][1][r]),
                                   fmaxf(sa[m][2][r], sa[m][3][r]));
        #pragma unroll
        for (int d = 1; d < 16; d <<= 1)
            #pragma unroll
            for (int m = 0; m < 2; ++m)
                #pragma unroll
                for (int r = 0; r < 4; ++r)
                    pmax[m][r] = fmaxf(pmax[m][r], __shfl_xor(pmax[m][r], d, 64));
        if (c15 == 0) {
            #pragma unroll
            for (int m = 0; m < 2; ++m)
                #pragma unroll
                for (int r = 0; r < 4; ++r)
                    red_max[w * 32 + m * 16 + q * 4 + r] = pmax[m][r];
        }
        __syncthreads();                              // B1
        float mnew[2][4], alpha[2][4];
        #pragma unroll
        for (int m = 0; m < 2; ++m)
            #pragma unroll
            for (int r = 0; r < 4; ++r) {
                int j = m * 16 + q * 4 + r;
                float t = fmaxf(fmaxf(red_max[j], red_max[32 + j]),
                                fmaxf(red_max[64 + j], red_max[96 + j]));
                float mn = fmaxf(m_run[m][r], t);
                mnew[m][r] = mn;
                alpha[m][r] = __expf(m_run[m][r] - mn);
                m_run[m][r] = mn;
            }
        float psum[2][4] = {};
        #pragma unroll
        for (int m = 0; m < 2; ++m)
            #pragma unroll
            for (int n = 0; n < 4; ++n)
                #pragma unroll
                for (int r = 0; r < 4; ++r) {
                    float p = __expf(sa[m][n][r] - mnew[m][r]);
                    sa[m][n][r] = p;
                    psum[m][r] += p;
                }
        #pragma unroll
        for (int d = 1; d < 16; d <<= 1)
            #pragma unroll
            for (int m = 0; m < 2; ++m)
                #pragma unroll
                for (int r = 0; r < 4; ++r)
                    psum[m][r] += __shfl_xor(psum[m][r], d, 64);
        if (c15 == 0) {
            #pragma unroll
            for (int m = 0; m < 2; ++m)
                #pragma unroll
                for (int r = 0; r < 4; ++r)
                    red_sum[w * 32 + m * 16 + q * 4 + r] = psum[m][r];
        }
        if (w < 2) {                                  // Pf half 0 (c 0..127)
            #pragma unroll
            for (int m = 0; m < 2; ++m)
                #pragma unroll
                for (int n = 0; n < 4; ++n)
                    #pragma unroll
                    for (int r = 0; r < 4; ++r) {
                        int cl = w * 64 + n * 16 + c15;
                        int c32h = cl >> 5, co = cl & 31;
                        int lp = (q * 4 + r) + 16 * (co >> 3);
                        Pf[((m * 4 + c32h) * 64 + lp) * 8 + (co & 7)] = f2bf_rn(sa[m][n][r]);
                    }
        }
        __syncthreads();                              // B2
        #pragma unroll
        for (int m = 0; m < 2; ++m)
            #pragma unroll
            for (int r = 0; r < 4; ++r) {
                int j = m * 16 + q * 4 + r;
                float ts = red_sum[j] + red_sum[32 + j] + red_sum[64 + j] + red_sum[96 + j];
                l_run[m][r] = l_run[m][r] * alpha[m][r] + ts;
            }
        #pragma unroll
        for (int m = 0; m < 2; ++m)
            #pragma unroll
            for (int n = 0; n < 8; ++n)
                #pragma unroll
                for (int r = 0; r < 4; ++r) o[m][n][r] *= alpha[m][r];

        // ---- PV in two c-halves of 128 (Xt aliases XW region) ----
        for (int hh = 0; hh < 2; ++hh) {
            if (hh == 1) {
                __syncthreads();                      // half-0 pa reads done
                if (w >= 2) {
                    #pragma unroll
                    for (int m = 0; m < 2; ++m)
                        #pragma unroll
                        for (int n = 0; n < 4; ++n)
                            #pragma unroll
                            for (int r = 0; r < 4; ++r) {
                                int cl = w * 64 + n * 16 + c15 - 128;
                                int c32h = cl >> 5, co = cl & 31;
                                int lp = (q * 4 + r) + 16 * (co >> 3);
                                Pf[((m * 4 + c32h) * 64 + lp) * 8 + (co & 7)] = f2bf_rn(sa[m][n][r]);
                            }
                }
            }
            for (int cc = 0; cc < 4; ++cc) {
                __syncthreads();
                #pragma unroll
                for (int i = 0; i < 8; ++i) {         // Xt: 32 segs
                    int dd16 = w + 4 * i;
                    int c32 = sp * 32 + xt * 8 + hh * 4 + cc;
                    const unsigned short* src =
                        xtf + (((size_t)(b * 32 + dd16)) * 64 + c32) * 512 + lane * 8;
                    async16(smem + dd16 * 1024 + lane * 16, src);
                }
                __syncthreads();
                bf16x8 pa0 = ldfrag(smem + 36864 + ((cc) * 64 + lane) * 16);
                bf16x8 pa1 = ldfrag(smem + 36864 + ((4 + cc) * 64 + lane) * 16);
                #pragma unroll
                for (int n = 0; n < 8; ++n) {
                    bf16x8 xb = ldfrag(smem + (w * 8 + n) * 1024 + lane * 16);
                    o[0][n] = __builtin_amdgcn_mfma_f32_16x16x32_bf16(pa0, xb, o[0][n], 0, 0, 0);
                    o[1][n] = __builtin_amdgcn_mfma_f32_16x16x32_bf16(pa1, xb, o[1][n], 0, 0, 0);
                }
            }
        }
    }

    // ---- epilogue: fp16 normalized partial + (m,l) ----
    #pragma unroll
    for (int m = 0; m < 2; ++m)
        #pragma unroll
        for (int r = 0; r < 4; ++r) {
            float inv = 1.0f / l_run[m][r];
            int j = jt * 32 + m * 16 + q * 4 + r;
            size_t row = ((size_t)sp * 8 + b) * 2048 + j;
            #pragma unroll
            for (int n = 0; n < 8; ++n) {
                int dd = w * 128 + n * 16 + c15;
                part[row * 512 + dd] = __float2half(o[m][n][r] * inv);
            }
        }
    if (w == 0 && c15 == 0) {
        #pragma unroll
        for (int m = 0; m < 2; ++m)
            #pragma unroll
            for (int r = 0; r < 4; ++r) {
                int j = jt * 32 + m * 16 + q * 4 + r;
                size_t row = ((size_t)sp * 8 + b) * 2048 + j;
                mpart[row] = m_run[m][r];
                lpart[row] = l_run[m][r];
            }
    }
}

// ---------------------------------------------------------------------------
// k3: combine the two c-split partials. out = (b0*P0 + b1*P1), b_s = softmax wt.
// ---------------------------------------------------------------------------
__global__ __launch_bounds__(256) void combine_k(
    const __half* __restrict__ part, const float* __restrict__ mp,
    const float* __restrict__ lp, float* __restrict__ out)
{
    int t = blockIdx.x * 256 + threadIdx.x;
    int row = t >> 6;
    int d8 = (t & 63) * 8;
    float m0 = mp[row], m1 = mp[16384 + row];
    float l0 = lp[row], l1 = lp[16384 + row];
    float M = fmaxf(m0, m1);
    float b0 = l0 * __expf(m0 - M);
    float b1 = l1 * __expf(m1 - M);
    float inv = 1.0f / (b0 + b1);
    b0 *= inv; b1 *= inv;
    const __half2* p0 = (const __half2*)(part + (size_t)row * 512 + d8);
    const __half2* p1 = (const __half2*)(part + 8388608 + (size_t)row * 512 + d8);
    float* og = out + (size_t)row * 512 + d8;
    #pragma unroll
    for (int i = 0; i < 4; ++i) {
        float2 a = __half22float2(p0[i]);
        float2 c = __half22float2(p1[i]);
        og[2 * i + 0] = b0 * a.x + b1 * c.x;
        og[2 * i + 1] = b0 * a.y + b1 * c.y;
    }
}

// ---------------------------------------------------------------------------
// Fallback fp32 path if ws_size is too small for the fast path.
// ---------------------------------------------------------------------------
__global__ __launch_bounds__(256) void xw_gemm_fb(
    const float* __restrict__ x, const float* __restrict__ Wb, float* __restrict__ xw)
{
    __shared__ float As[16][68];
    __shared__ float Bs[16][68];
    const int tid = threadIdx.x;
    const int bm = blockIdx.x * 64, bn = blockIdx.y * 64;
    const int tm = (tid & 15) * 4, tn = (tid >> 4) * 4;
    const int lrow = tid >> 2, lk = (tid & 3) * 4;
    const float* ag = x  + (size_t)(bm + lrow) * D_DIM + lk;
    const float* bg = Wb + (size_t)(bn + lrow) * D_DIM + lk;
    float acc[4][4] = {};
    for (int kt = 0; kt < D_DIM; kt += 16) {
        const float4 av = *(const float4*)(ag + kt);
        const float4 bv = *(const float4*)(bg + kt);
        __syncthreads();
        As[lk+0][lrow] = av.x; As[lk+1][lrow] = av.y; As[lk+2][lrow] = av.z; As[lk+3][lrow] = av.w;
        Bs[lk+0][lrow] = bv.x; Bs[lk+1][lrow] = bv.y; Bs[lk+2][lrow] = bv.z; Bs[lk+3][lrow] = bv.w;
        __syncthreads();
        #pragma unroll
        for (int k = 0; k < 16; ++k) {
            const float4 a = *(const float4*)&As[k][tm];
            const float4 bq = *(const float4*)&Bs[k][tn];
            const float* ap = (const float*)&a;
            const float* bp = (const float*)&bq;
            #pragma unroll
            for (int i = 0; i < 4; ++i)
                #pragma unroll
                for (int jj = 0; jj < 4; ++jj)
                    acc[i][jj] = fmaf(ap[i], bp[jj], acc[i][jj]);
        }
    }
    #pragma unroll
    for (int i = 0; i < 4; ++i)
        *(float4*)&xw[(size_t)(bm + tm + i) * D_DIM + bn + tn] =
            make_float4(acc[i][0], acc[i][1], acc[i][2], acc[i][3]);
}

__global__ __launch_bounds__(256) void flash_fb(
    const float* __restrict__ x, const float* __restrict__ y,
    const float* __restrict__ xw, float* __restrict__ out)
{
    __shared__ float Yl[16][516];
    __shared__ float XWl[64][68];
    __shared__ float Pl[16][68];
    __shared__ float Xl[8][512];
    const int tid = threadIdx.x, b = blockIdx.y, jtb = blockIdx.x;
    const int j = tid >> 4, tc = tid & 15, c0 = tc * 4;
    {
        const float* yg = y + (size_t)(b * LY + jtb * 16 + j) * D_DIM;
        #pragma unroll
        for (int ii = 0; ii < 8; ++ii)
            *(float4*)&Yl[j][tc * 4 + 64 * ii] = *(const float4*)(yg + tc * 4 + 64 * ii);
    }
    float4 o[8];
    #pragma unroll
    for (int ii = 0; ii < 8; ++ii) o[ii] = make_float4(0.f, 0.f, 0.f, 0.f);
    float m = -INFINITY, l = 0.f;
    const size_t xbase = (size_t)b * LX * D_DIM;
    for (int xtt = 0; xtt < LX / 64; ++xtt) {
        float sa[4] = {0.f, 0.f, 0.f, 0.f};
        for (int kcc = 0; kcc < D_DIM; kcc += 64) {
            const int sc = tid >> 2, skq = (tid & 3) * 4;
            const float* xwg = xw + xbase + (size_t)(xtt * 64 + sc) * D_DIM + kcc + skq;
            const float4 t0 = *(const float4*)(xwg + 0);
            const float4 t1 = *(const float4*)(xwg + 16);
            const float4 t2 = *(const float4*)(xwg + 32);
            const float4 t3 = *(const float4*)(xwg + 48);
            __syncthreads();
            XWl[skq+ 0][sc]=t0.x; XWl[skq+ 1][sc]=t0.y; XWl[skq+ 2][sc]=t0.z; XWl[skq+ 3][sc]=t0.w;
            XWl[skq+16][sc]=t1.x; XWl[skq+17][sc]=t1.y; XWl[skq+18][sc]=t1.z; XWl[skq+19][sc]=t1.w;
            XWl[skq+32][sc]=t2.x; XWl[skq+33][sc]=t2.y; XWl[skq+34][sc]=t2.z; XWl[skq+35][sc]=t2.w;
            XWl[skq+48][sc]=t3.x; XWl[skq+49][sc]=t3.y; XWl[skq+50][sc]=t3.z; XWl[skq+51][sc]=t3.w;
            __syncthreads();
            #pragma unroll
            for (int k4 = 0; k4 < 16; ++k4) {
                const float4 yv = *(const float4*)&Yl[j][kcc + k4 * 4];
                const float* yp = (const float*)&yv;
                #pragma unroll
                for (int ss = 0; ss < 4; ++ss) {
                    const float4 xv = *(const float4*)&XWl[k4 * 4 + ss][c0];
                    sa[0] = fmaf(yp[ss], xv.x, sa[0]);
                    sa[1] = fmaf(yp[ss], xv.y, sa[1]);
                    sa[2] = fmaf(yp[ss], xv.z, sa[2]);
                    sa[3] = fmaf(yp[ss], xv.w, sa[3]);
                }
            }
        }
        float tmax = fmaxf(fmaxf(sa[0], sa[1]), fmaxf(sa[2], sa[3]));
        #pragma unroll
        for (int ww = 1; ww < 16; ww <<= 1) tmax = fmaxf(tmax, __shfl_xor(tmax, ww, 64));
        const float mnew = fmaxf(m, tmax);
        const float scale = __expf(m - mnew);
        const float p0 = __expf(sa[0] - mnew), p1 = __expf(sa[1] - mnew);
        const float p2 = __expf(sa[2] - mnew), p3 = __expf(sa[3] - mnew);
        float ts = p0 + p1 + p2 + p3;
        #pragma unroll
        for (int ww = 1; ww < 16; ww <<= 1) ts += __shfl_xor(ts, ww, 64);
        l = l * scale + ts; m = mnew;
        #pragma unroll
        for (int ii = 0; ii < 8; ++ii) {
            o[ii].x *= scale; o[ii].y *= scale; o[ii].z *= scale; o[ii].w *= scale;
        }
        *(float4*)&Pl[j][c0] = make_float4(p0, p1, p2, p3);
        for (int ccc = 0; ccc < 8; ++ccc) {
            const int xr = tid >> 5, xq = (tid & 31) * 4;
            const float* xg = x + xbase + (size_t)(xtt * 64 + ccc * 8 + xr) * D_DIM + xq;
            const float4 x0 = *(const float4*)(xg + 0);
            const float4 x1 = *(const float4*)(xg + 128);
            const float4 x2 = *(const float4*)(xg + 256);
            const float4 x3 = *(const float4*)(xg + 384);
            __syncthreads();
            *(float4*)&Xl[xr][xq +   0] = x0; *(float4*)&Xl[xr][xq + 128] = x1;
            *(float4*)&Xl[xr][xq + 256] = x2; *(float4*)&Xl[xr][xq + 384] = x3;
            __syncthreads();
            #pragma unroll
            for (int c = 0; c < 8; ++c) {
                const float pv = Pl[j][ccc * 8 + c];
                #pragma unroll
                for (int ii = 0; ii < 8; ++ii) {
                    const float4 xv = *(const float4*)&Xl[c][tc * 4 + 64 * ii];
                    o[ii].x = fmaf(pv, xv.x, o[ii].x); o[ii].y = fmaf(pv, xv.y, o[ii].y);
                    o[ii].z = fmaf(pv, xv.z, o[ii].z); o[ii].w = fmaf(pv, xv.w, o[ii].w);
                }
            }
        }
    }
    const float inv = 1.0f / l;
    float* og = out + (size_t)(b * LY + jtb * 16 + j) * D_DIM;
    #pragma unroll
    for (int ii = 0; ii < 8; ++ii) {
        float4 v = o[ii];
        v.x *= inv; v.y *= inv; v.z *= inv; v.w *= inv;
        *(float4*)(og + tc * 4 + 64 * ii) = v;
    }
}

// ---------------------------------------------------------------------------
extern "C" void kernel_launch(void* const* d_in, const int* in_sizes, int n_in,
                              void* d_out, int out_size, void* d_ws, size_t ws_size,
                              hipStream_t stream)
{
    const float* x  = (const float*)d_in[0];
    const float* y  = (const float*)d_in[1];
    const float* Wb = (const float*)d_in[2];
    float* out = (float*)d_out;

    // ws layout (bytes). part (fp16, 33.5 MB) aliases xfh/xfl (dead after xw_mfma);
    // mpart/lpart alias wfh (dead after xw_mfma).
    const size_t OFF_XFH = 0,         OFF_XFL = 16777216;
    const size_t OFF_YFH = 33554432,  OFF_YFL = 50331648;
    const size_t OFF_XTF = 67108864;
    const size_t OFF_XWH = 83886080,  OFF_XWL = 100663296;
    const size_t OFF_WFH = 117440512, OFF_WFL = 117964800;
    const size_t NEEDED  = 118489088;

    if (ws_size >= NEEDED) {
        char* ws = (char*)d_ws;
        unsigned short* xfh = (unsigned short*)(ws + OFF_XFH);
        unsigned short* xfl = (unsigned short*)(ws + OFF_XFL);
        unsigned short* yfh = (unsigned short*)(ws + OFF_YFH);
        unsigned short* yfl = (unsigned short*)(ws + OFF_YFL);
        unsigned short* xtf = (unsigned short*)(ws + OFF_XTF);
        unsigned short* xwfh = (unsigned short*)(ws + OFF_XWH);
        unsigned short* xwfl = (unsigned short*)(ws + OFF_XWL);
        unsigned short* wfh = (unsigned short*)(ws + OFF_WFH);
        unsigned short* wfl = (unsigned short*)(ws + OFF_WFL);
        __half* part = (__half*)(ws + OFF_XFH);
        float* mpart = (float*)(ws + OFF_WFH);
        float* lpart = (float*)(ws + OFF_WFH + 131072);

        repack_hilo_k<<<4096, 256, 0, stream>>>(x, xfh, xfl, 16384);
        repack_hilo_k<<<4096, 256, 0, stream>>>(y, yfh, yfl, 16384);
        repack_hilo_k<<<128, 256, 0, stream>>>(Wb, wfh, wfl, 512);
        dim3 gt(32, 8, 8);
        xt_repack_k<<<gt, 256, 0, stream>>>(x, xtf);
        dim3 g1(128, 8);
        xw_mfma_k<<<g1, 256, 0, stream>>>(xfh, xfl, wfh, wfl, xwfh, xwfl);
        dim3 g2(64, 2, 8);
        flash2_k<<<g2, 256, 0, stream>>>(yfh, yfl, xwfh, xwfl, xtf, part, mpart, lpart);
        combine_k<<<4096, 256, 0, stream>>>(part, mpart, lpart, out);
    } else {
        float* xw = (float*)d_ws;
        dim3 g1(NB * LX / 64, D_DIM / 64);
        xw_gemm_fb<<<g1, 256, 0, stream>>>(x, Wb, xw);
        dim3 g2(LY / 16, NB);
        flash_fb<<<g2, 256, 0, stream>>>(x, y, xw, out);
    }
}

// Round 4
// 383.619 us; speedup vs baseline: 1.6280x; 1.6280x over previous
//
#include <hip/hip_runtime.h>
#include <hip/hip_bf16.h>
#include <math.h>

#define D_DIM 512
#define LX 2048
#define LY 2048
#define NB 8

typedef float f32x4 __attribute__((ext_vector_type(4)));
typedef __bf16 bf16x8 __attribute__((ext_vector_type(8)));

__device__ __forceinline__ unsigned short f2bf_rn(float f) {
    unsigned u = __float_as_uint(f);
    unsigned r = (u + 0x7fffu + ((u >> 16) & 1u)) >> 16;
    return (unsigned short)r;
}
__device__ __forceinline__ float bf2f(unsigned short h) {
    return __uint_as_float(((unsigned)h) << 16);
}
__device__ __forceinline__ void async16(void* lds, const void* g) {
    __builtin_amdgcn_global_load_lds(
        (const __attribute__((address_space(1))) void*)g,
        (__attribute__((address_space(3))) void*)lds, 16, 0, 0);
}
__device__ __forceinline__ bf16x8 ldfrag(const char* p) {
    return *(const bf16x8*)p;
}

// ---------------------------------------------------------------------------
// prep_k: fused prologue (one launch instead of four).
//   blocks [0,4096)    : x  -> xfh/xfl  (frag-order hi/lo)
//   blocks [4096,8192) : y  -> yfh/yfl
//   blocks [8192,8320) : Wb -> wfh/wfl
//   blocks [8320,10368): x  -> xtf (transposed frag-order, bf16 hi only)
// frag block fb = r16*16 + k32; lane = row%16 + 16*((k%32)/8); elems = k%8.
// ---------------------------------------------------------------------------
__global__ __launch_bounds__(256) void prep_k(
    const float* __restrict__ x, const float* __restrict__ y,
    const float* __restrict__ Wb,
    unsigned short* __restrict__ xfh, unsigned short* __restrict__ xfl,
    unsigned short* __restrict__ yfh, unsigned short* __restrict__ yfl,
    unsigned short* __restrict__ wfh, unsigned short* __restrict__ wfl,
    unsigned short* __restrict__ xtf)
{
    __shared__ unsigned short T2[64][72];
    const int blk = blockIdx.x, tid = threadIdx.x;

    if (blk < 8320) {
        const float* src; unsigned short *dh, *dl; int base;
        if (blk < 4096)      { src = x;  dh = xfh; dl = xfl; base = blk; }
        else if (blk < 8192) { src = y;  dh = yfh; dl = yfl; base = blk - 4096; }
        else                 { src = Wb; dh = wfh; dl = wfl; base = blk - 8192; }
        int fbid = base * 4 + (tid >> 6);
        int lane = tid & 63;
        int r16 = fbid >> 4, k32 = fbid & 15;
        int row = r16 * 16 + (lane & 15);
        int col = k32 * 32 + (lane >> 4) * 8;
        const float* s = src + (size_t)row * D_DIM + col;
        float4 v0 = *(const float4*)s;
        float4 v1 = *(const float4*)(s + 4);
        float vv[8] = {v0.x, v0.y, v0.z, v0.w, v1.x, v1.y, v1.z, v1.w};
        unsigned hh[4], ll[4];
        #pragma unroll
        for (int k = 0; k < 4; ++k) {
            unsigned short ha = f2bf_rn(vv[2*k]),   hb = f2bf_rn(vv[2*k+1]);
            unsigned short la = f2bf_rn(vv[2*k]   - bf2f(ha));
            unsigned short lb = f2bf_rn(vv[2*k+1] - bf2f(hb));
            hh[k] = (unsigned)ha | ((unsigned)hb << 16);
            ll[k] = (unsigned)la | ((unsigned)lb << 16);
        }
        size_t off = (size_t)fbid * 512 + lane * 8;
        *(uint4*)(dh + off) = make_uint4(hh[0], hh[1], hh[2], hh[3]);
        *(uint4*)(dl + off) = make_uint4(ll[0], ll[1], ll[2], ll[3]);
    } else {
        int idx = blk - 8320;
        int ct = idx & 31, dt = (idx >> 5) & 7, b = idx >> 8;
        const float* xb = x + (size_t)b * LX * D_DIM;
        int rc = tid >> 4;
        int d4 = (tid & 15) * 4;
        #pragma unroll
        for (int i = 0; i < 4; ++i) {
            int cl = rc + i * 16;
            float4 v = *(const float4*)(xb + (size_t)(ct * 64 + cl) * D_DIM + dt * 64 + d4);
            T2[d4 + 0][cl] = f2bf_rn(v.x);
            T2[d4 + 1][cl] = f2bf_rn(v.y);
            T2[d4 + 2][cl] = f2bf_rn(v.z);
            T2[d4 + 3][cl] = f2bf_rn(v.w);
        }
        __syncthreads();
        #pragma unroll
        for (int si = 0; si < 2; ++si) {
            int s = tid + si * 256;
            int fb = s >> 6, lane = s & 63;
            int dd16l = fb >> 1, c32l = fb & 1;
            int ddl = dd16l * 16 + (lane & 15);
            int cl  = c32l * 32 + (lane >> 4) * 8;
            uint4 v = *(const uint4*)&T2[ddl][cl];
            size_t off = ((size_t)((b * 32 + dt * 4 + dd16l) * 64 + (ct * 2 + c32l)) * 64 + lane) * 8;
            *(uint4*)(xtf + off) = v;
        }
    }
}

// ---------------------------------------------------------------------------
// k1: xw = x @ Wb^T, 3-term hi/lo MFMA, single-barrier double-buffered K-loop.
// Block 128x64, 4 waves. Chunk = K32: A 16 KB + B 8 KB = 24 KB; 2 bufs.
// ---------------------------------------------------------------------------
__global__ __launch_bounds__(256, 2) void xw_mfma_k(
    const unsigned short* __restrict__ xfh, const unsigned short* __restrict__ xfl,
    const unsigned short* __restrict__ wfh, const unsigned short* __restrict__ wfl,
    unsigned short* __restrict__ xwfh, unsigned short* __restrict__ xwfl)
{
    __shared__ char smem[49152];   // 2 x 24576 chunk bufs; epilogue E fp32 [128][68]
    const int tid = threadIdx.x, lane = tid & 63, w = tid >> 6;
    const int Mt = blockIdx.x, Nt = blockIdx.y;

    f32x4 acc[2][4];
    #pragma unroll
    for (int m = 0; m < 2; ++m)
        #pragma unroll
        for (int n = 0; n < 4; ++n) acc[m][n] = (f32x4){0.f, 0.f, 0.f, 0.f};

    auto stage = [&](int kc, int buf) {
        char* sb = smem + buf * 24576;
        #pragma unroll
        for (int i = 0; i < 4; ++i) {                 // A: 16 segs (8 c16 x hi/lo)
            int s = w + 4 * i;
            int c16l = s >> 1, h = s & 1;
            size_t fb = ((size_t)(Mt * 8 + c16l)) * 16 + kc;
            const unsigned short* src = (h ? xfl : xfh) + fb * 512 + lane * 8;
            async16(sb + h * 8192 + c16l * 1024 + lane * 16, src);
        }
        #pragma unroll
        for (int i = 0; i < 2; ++i) {                 // B: 8 segs (4 n16 x hi/lo)
            int s = w + 4 * i;
            int n16l = s >> 1, h = s & 1;
            size_t fb = ((size_t)(Nt * 4 + n16l)) * 16 + kc;
            const unsigned short* src = (h ? wfl : wfh) + fb * 512 + lane * 8;
            async16(sb + 16384 + h * 4096 + n16l * 1024 + lane * 16, src);
        }
    };

    stage(0, 0);
    __syncthreads();
    for (int kc = 0; kc < 16; ++kc) {
        if (kc < 15) stage(kc + 1, (kc + 1) & 1);     // prefetch next chunk
        char* sb = smem + (kc & 1) * 24576;
        bf16x8 ah[2], al[2], bh[4], bl[4];
        #pragma unroll
        for (int m = 0; m < 2; ++m) {
            int c16l = w * 2 + m;
            ah[m] = ldfrag(sb + c16l * 1024 + lane * 16);
            al[m] = ldfrag(sb + 8192 + c16l * 1024 + lane * 16);
        }
        #pragma unroll
        for (int n = 0; n < 4; ++n) {
            bh[n] = ldfrag(sb + 16384 + n * 1024 + lane * 16);
            bl[n] = ldfrag(sb + 20480 + n * 1024 + lane * 16);
        }
        #pragma unroll
        for (int m = 0; m < 2; ++m)
            #pragma unroll
            for (int n = 0; n < 4; ++n) {
                acc[m][n] = __builtin_amdgcn_mfma_f32_16x16x32_bf16(ah[m], bh[n], acc[m][n], 0, 0, 0);
                acc[m][n] = __builtin_amdgcn_mfma_f32_16x16x32_bf16(ah[m], bl[n], acc[m][n], 0, 0, 0);
                acc[m][n] = __builtin_amdgcn_mfma_f32_16x16x32_bf16(al[m], bh[n], acc[m][n], 0, 0, 0);
            }
        __syncthreads();                              // drains prefetch post-compute
    }

    // epilogue: LDS transpose -> frag-order hi/lo
    float* E = (float*)smem;
    const int q = lane >> 4, c15 = lane & 15;
    #pragma unroll
    for (int m = 0; m < 2; ++m)
        #pragma unroll
        for (int n = 0; n < 4; ++n)
            #pragma unroll
            for (int r = 0; r < 4; ++r)
                E[(w * 32 + m * 16 + q * 4 + r) * 68 + n * 16 + c15] = acc[m][n][r];
    __syncthreads();
    #pragma unroll
    for (int i = 0; i < 4; ++i) {
        int s = tid + i * 256;
        int c16l = s >> 7, e32l = (s >> 6) & 1, lp = s & 63;
        int row = c16l * 16 + (lp & 15), col = e32l * 32 + (lp >> 4) * 8;
        const float* sp = E + row * 68 + col;
        unsigned hh[4], ll[4];
        #pragma unroll
        for (int k = 0; k < 4; ++k) {
            float a = sp[2 * k], bq = sp[2 * k + 1];
            unsigned short ha = f2bf_rn(a), hb = f2bf_rn(bq);
            unsigned short la = f2bf_rn(a - bf2f(ha)), lb = f2bf_rn(bq - bf2f(hb));
            hh[k] = (unsigned)ha | ((unsigned)hb << 16);
            ll[k] = (unsigned)la | ((unsigned)lb << 16);
        }
        size_t fb = (size_t)(Mt * 8 + c16l) * 16 + (Nt * 2 + e32l);
        *(uint4*)(xwfh + fb * 512 + lp * 8) = make_uint4(hh[0], hh[1], hh[2], hh[3]);
        *(uint4*)(xwfl + fb * 512 + lp * 8) = make_uint4(ll[0], ll[1], ll[2], ll[3]);
    }
}

// ---------------------------------------------------------------------------
// k2: flash bilinear attention v3. Block 32j x 128c, 4 waves, no split.
// Single-barrier double-buffered staging for both S (K=32 chunks, 2x20 KB)
// and PV (Xt c32 chunks, 2x32 KB, aliasing the S region). 3-term hi/lo S.
// LDS 73 KB: stage/Xt [0,65536), Pf [65536,73728), red [73728,74752).
// ---------------------------------------------------------------------------
#define SBUF_STRIDE 20480

__global__ __launch_bounds__(256, 2) void flash3_k(
    const unsigned short* __restrict__ yfh, const unsigned short* __restrict__ yfl,
    const unsigned short* __restrict__ xwfh, const unsigned short* __restrict__ xwfl,
    const unsigned short* __restrict__ xtf, float* __restrict__ out)
{
    __shared__ char smem[74752];
    const int tid = threadIdx.x, lane = tid & 63, w = tid >> 6;
    const int jt = blockIdx.x, b = blockIdx.y;
    const int q = lane >> 4, c15 = lane & 15;
    unsigned short* Pf = (unsigned short*)(smem + 65536);
    float* red_max = (float*)(smem + 73728);
    float* red_sum = (float*)(smem + 74240);

    f32x4 o[2][8];
    #pragma unroll
    for (int m = 0; m < 2; ++m)
        #pragma unroll
        for (int n = 0; n < 8; ++n) o[m][n] = (f32x4){0.f, 0.f, 0.f, 0.f};
    float m_run[2][4], l_run[2][4];
    #pragma unroll
    for (int m = 0; m < 2; ++m)
        #pragma unroll
        for (int r = 0; r < 4; ++r) { m_run[m][r] = -INFINITY; l_run[m][r] = 0.f; }

    // S-chunk layout (20480 B): XW hi [0,8K) 8x1KB, XW lo [8K,16K),
    //                           Y hi [16K,18K) 2x1KB, Y lo [18K,20K).
    auto stage_s = [&](int xt, int kc, int buf) {
        char* sb = smem + buf * SBUF_STRIDE;
        #pragma unroll
        for (int i = 0; i < 4; ++i) {                 // XW: 16 segs
            int s = w + 4 * i;
            int c16l = s >> 1, h = s & 1;
            size_t fb = ((size_t)(b * 128 + xt * 8 + c16l)) * 16 + kc;
            const unsigned short* src = (h ? xwfl : xwfh) + fb * 512 + lane * 8;
            async16(sb + h * 8192 + c16l * 1024 + lane * 16, src);
        }
        {                                             // Y: 4 segs (one per wave)
            int j16l = w & 1, h = w >> 1;
            size_t fb = ((size_t)(b * 128 + jt * 2 + j16l)) * 16 + kc;
            const unsigned short* src = (h ? yfl : yfh) + fb * 512 + lane * 8;
            async16(sb + 16384 + h * 2048 + j16l * 1024 + lane * 16, src);
        }
    };
    // Xt chunk (32768 B): 32 dd16 blocks x 1 KB, chunk covers one c32.
    auto stage_x = [&](int xt, int cc, int buf) {
        char* xb = smem + buf * 32768;
        #pragma unroll
        for (int i = 0; i < 8; ++i) {
            int dd16 = w + 4 * i;
            size_t off = (((size_t)(b * 32 + dd16)) * 64 + (xt * 4 + cc)) * 512 + lane * 8;
            async16(xb + dd16 * 1024 + lane * 16, xtf + off);
        }
    };

    for (int xt = 0; xt < 16; ++xt) {
        f32x4 sa[2][2];
        #pragma unroll
        for (int m = 0; m < 2; ++m)
            #pragma unroll
            for (int n = 0; n < 2; ++n) sa[m][n] = (f32x4){0.f, 0.f, 0.f, 0.f};

        // ---- S: K=512 in 16 chunks of 32, dbuf, one barrier per chunk ----
        stage_s(xt, 0, 0);
        __syncthreads();
        for (int kc = 0; kc < 16; ++kc) {
            if (kc < 15) stage_s(xt, kc + 1, (kc + 1) & 1);
            char* sb = smem + (kc & 1) * SBUF_STRIDE;
            bf16x8 ah[2], al[2];
            ah[0] = ldfrag(sb + 16384 + lane * 16);
            ah[1] = ldfrag(sb + 17408 + lane * 16);
            al[0] = ldfrag(sb + 18432 + lane * 16);
            al[1] = ldfrag(sb + 19456 + lane * 16);
            #pragma unroll
            for (int n = 0; n < 2; ++n) {
                int c16l = w * 2 + n;
                bf16x8 bh = ldfrag(sb + c16l * 1024 + lane * 16);
                bf16x8 bl = ldfrag(sb + 8192 + c16l * 1024 + lane * 16);
                #pragma unroll
                for (int m = 0; m < 2; ++m) {
                    sa[m][n] = __builtin_amdgcn_mfma_f32_16x16x32_bf16(ah[m], bh, sa[m][n], 0, 0, 0);
                    sa[m][n] = __builtin_amdgcn_mfma_f32_16x16x32_bf16(ah[m], bl, sa[m][n], 0, 0, 0);
                    sa[m][n] = __builtin_amdgcn_mfma_f32_16x16x32_bf16(al[m], bh, sa[m][n], 0, 0, 0);
                }
            }
            __syncthreads();                          // drains prefetch post-compute
        }

        // ---- online softmax (rows j = m*16 + q*4 + r) ----
        float pmax[2][4];
        #pragma unroll
        for (int m = 0; m < 2; ++m)
            #pragma unroll
            for (int r = 0; r < 4; ++r) pmax[m][r] = fmaxf(sa[m][0][r], sa[m][1][r]);
        #pragma unroll
        for (int d = 1; d < 16; d <<= 1)
            #pragma unroll
            for (int m = 0; m < 2; ++m)
                #pragma unroll
                for (int r = 0; r < 4; ++r)
                    pmax[m][r] = fmaxf(pmax[m][r], __shfl_xor(pmax[m][r], d, 64));
        if (c15 == 0) {
            #pragma unroll
            for (int m = 0; m < 2; ++m)
                #pragma unroll
                for (int r = 0; r < 4; ++r)
                    red_max[w * 32 + m * 16 + q * 4 + r] = pmax[m][r];
        }
        __syncthreads();                              // B1
        float mnew[2][4], alpha[2][4];
        #pragma unroll
        for (int m = 0; m < 2; ++m)
            #pragma unroll
            for (int r = 0; r < 4; ++r) {
                int j = m * 16 + q * 4 + r;
                float t = fmaxf(fmaxf(red_max[j], red_max[32 + j]),
                                fmaxf(red_max[64 + j], red_max[96 + j]));
                float mn = fmaxf(m_run[m][r], t);
                mnew[m][r] = mn;
                alpha[m][r] = __expf(m_run[m][r] - mn);
                m_run[m][r] = mn;
            }
        float psum[2][4] = {};
        #pragma unroll
        for (int m = 0; m < 2; ++m)
            #pragma unroll
            for (int n = 0; n < 2; ++n)
                #pragma unroll
                for (int r = 0; r < 4; ++r) {
                    float p = __expf(sa[m][n][r] - mnew[m][r]);
                    sa[m][n][r] = p;
                    psum[m][r] += (n == 0) ? p - psum[m][r] * 0.f : p;  // just add
                }
        #pragma unroll
        for (int d = 1; d < 16; d <<= 1)
            #pragma unroll
            for (int m = 0; m < 2; ++m)
                #pragma unroll
                for (int r = 0; r < 4; ++r)
                    psum[m][r] += __shfl_xor(psum[m][r], d, 64);
        if (c15 == 0) {
            #pragma unroll
            for (int m = 0; m < 2; ++m)
                #pragma unroll
                for (int r = 0; r < 4; ++r)
                    red_sum[w * 32 + m * 16 + q * 4 + r] = psum[m][r];
        }
        // P -> A-frag layout in LDS (wave w owns c32 block w of the 128-tile)
        #pragma unroll
        for (int m = 0; m < 2; ++m)
            #pragma unroll
            for (int n = 0; n < 2; ++n)
                #pragma unroll
                for (int r = 0; r < 4; ++r) {
                    int cl = n * 16 + c15;           // col within wave's c32
                    int lp = (q * 4 + r) + 16 * (cl >> 3);
                    Pf[((m * 4 + w) * 64 + lp) * 8 + (cl & 7)] = f2bf_rn(sa[m][n][r]);
                }
        __syncthreads();                              // B2: Pf + red_sum visible
        #pragma unroll
        for (int m = 0; m < 2; ++m)
            #pragma unroll
            for (int r = 0; r < 4; ++r) {
                int j = m * 16 + q * 4 + r;
                float ts = red_sum[j] + red_sum[32 + j] + red_sum[64 + j] + red_sum[96 + j];
                l_run[m][r] = l_run[m][r] * alpha[m][r] + ts;
            }
        #pragma unroll
        for (int m = 0; m < 2; ++m)
            #pragma unroll
            for (int n = 0; n < 8; ++n)
                #pragma unroll
                for (int r = 0; r < 4; ++r) o[m][n][r] *= alpha[m][r];

        // ---- PV: 4 c32 chunks, dbuf, one barrier per chunk ----
        stage_x(xt, 0, 0);
        __syncthreads();
        for (int cc = 0; cc < 4; ++cc) {
            if (cc < 3) stage_x(xt, cc + 1, (cc + 1) & 1);
            char* xb = smem + (cc & 1) * 32768;
            bf16x8 pa0 = ldfrag((const char*)Pf + ((0 * 4 + cc) * 64 + lane) * 16);
            bf16x8 pa1 = ldfrag((const char*)Pf + ((1 * 4 + cc) * 64 + lane) * 16);
            #pragma unroll
            for (int n = 0; n < 8; ++n) {
                bf16x8 xv = ldfrag(xb + (w * 8 + n) * 1024 + lane * 16);
                o[0][n] = __builtin_amdgcn_mfma_f32_16x16x32_bf16(pa0, xv, o[0][n], 0, 0, 0);
                o[1][n] = __builtin_amdgcn_mfma_f32_16x16x32_bf16(pa1, xv, o[1][n], 0, 0, 0);
            }
            __syncthreads();
        }
    }

    // ---- epilogue ----
    #pragma unroll
    for (int m = 0; m < 2; ++m)
        #pragma unroll
        for (int r = 0; r < 4; ++r) {
            float inv = 1.0f / l_run[m][r];
            int j = jt * 32 + m * 16 + q * 4 + r;
            #pragma unroll
            for (int n = 0; n < 8; ++n) {
                int dd = w * 128 + n * 16 + c15;
                out[((size_t)(b * 2048 + j)) * 512 + dd] = o[m][n][r] * inv;
            }
        }
}

// ---------------------------------------------------------------------------
// Fallback fp32 path if ws_size is too small for the fast path.
// ---------------------------------------------------------------------------
__global__ __launch_bounds__(256) void xw_gemm_fb(
    const float* __restrict__ x, const float* __restrict__ Wb, float* __restrict__ xw)
{
    __shared__ float As[16][68];
    __shared__ float Bs[16][68];
    const int tid = threadIdx.x;
    const int bm = blockIdx.x * 64, bn = blockIdx.y * 64;
    const int tm = (tid & 15) * 4, tn = (tid >> 4) * 4;
    const int lrow = tid >> 2, lk = (tid & 3) * 4;
    const float* ag = x  + (size_t)(bm + lrow) * D_DIM + lk;
    const float* bg = Wb + (size_t)(bn + lrow) * D_DIM + lk;
    float acc[4][4] = {};
    for (int kt = 0; kt < D_DIM; kt += 16) {
        const float4 av = *(const float4*)(ag + kt);
        const float4 bv = *(const float4*)(bg + kt);
        __syncthreads();
        As[lk+0][lrow] = av.x; As[lk+1][lrow] = av.y; As[lk+2][lrow] = av.z; As[lk+3][lrow] = av.w;
        Bs[lk+0][lrow] = bv.x; Bs[lk+1][lrow] = bv.y; Bs[lk+2][lrow] = bv.z; Bs[lk+3][lrow] = bv.w;
        __syncthreads();
        #pragma unroll
        for (int k = 0; k < 16; ++k) {
            const float4 a = *(const float4*)&As[k][tm];
            const float4 bq = *(const float4*)&Bs[k][tn];
            const float* ap = (const float*)&a;
            const float* bp = (const float*)&bq;
            #pragma unroll
            for (int i = 0; i < 4; ++i)
                #pragma unroll
                for (int jj = 0; jj < 4; ++jj)
                    acc[i][jj] = fmaf(ap[i], bp[jj], acc[i][jj]);
        }
    }
    #pragma unroll
    for (int i = 0; i < 4; ++i)
        *(float4*)&xw[(size_t)(bm + tm + i) * D_DIM + bn + tn] =
            make_float4(acc[i][0], acc[i][1], acc[i][2], acc[i][3]);
}

__global__ __launch_bounds__(256) void flash_fb(
    const float* __restrict__ x, const float* __restrict__ y,
    const float* __restrict__ xw, float* __restrict__ out)
{
    __shared__ float Yl[16][516];
    __shared__ float XWl[64][68];
    __shared__ float Pl[16][68];
    __shared__ float Xl[8][512];
    const int tid = threadIdx.x, b = blockIdx.y, jtb = blockIdx.x;
    const int j = tid >> 4, tc = tid & 15, c0 = tc * 4;
    {
        const float* yg = y + (size_t)(b * LY + jtb * 16 + j) * D_DIM;
        #pragma unroll
        for (int ii = 0; ii < 8; ++ii)
            *(float4*)&Yl[j][tc * 4 + 64 * ii] = *(const float4*)(yg + tc * 4 + 64 * ii);
    }
    float4 o[8];
    #pragma unroll
    for (int ii = 0; ii < 8; ++ii) o[ii] = make_float4(0.f, 0.f, 0.f, 0.f);
    float m = -INFINITY, l = 0.f;
    const size_t xbase = (size_t)b * LX * D_DIM;
    for (int xtt = 0; xtt < LX / 64; ++xtt) {
        float sa[4] = {0.f, 0.f, 0.f, 0.f};
        for (int kcc = 0; kcc < D_DIM; kcc += 64) {
            const int sc = tid >> 2, skq = (tid & 3) * 4;
            const float* xwg = xw + xbase + (size_t)(xtt * 64 + sc) * D_DIM + kcc + skq;
            const float4 t0 = *(const float4*)(xwg + 0);
            const float4 t1 = *(const float4*)(xwg + 16);
            const float4 t2 = *(const float4*)(xwg + 32);
            const float4 t3 = *(const float4*)(xwg + 48);
            __syncthreads();
            XWl[skq+ 0][sc]=t0.x; XWl[skq+ 1][sc]=t0.y; XWl[skq+ 2][sc]=t0.z; XWl[skq+ 3][sc]=t0.w;
            XWl[skq+16][sc]=t1.x; XWl[skq+17][sc]=t1.y; XWl[skq+18][sc]=t1.z; XWl[skq+19][sc]=t1.w;
            XWl[skq+32][sc]=t2.x; XWl[skq+33][sc]=t2.y; XWl[skq+34][sc]=t2.z; XWl[skq+35][sc]=t2.w;
            XWl[skq+48][sc]=t3.x; XWl[skq+49][sc]=t3.y; XWl[skq+50][sc]=t3.z; XWl[skq+51][sc]=t3.w;
            __syncthreads();
            #pragma unroll
            for (int k4 = 0; k4 < 16; ++k4) {
                const float4 yv = *(const float4*)&Yl[j][kcc + k4 * 4];
                const float* yp = (const float*)&yv;
                #pragma unroll
                for (int ss = 0; ss < 4; ++ss) {
                    const float4 xv = *(const float4*)&XWl[k4 * 4 + ss][c0];
                    sa[0] = fmaf(yp[ss], xv.x, sa[0]);
                    sa[1] = fmaf(yp[ss], xv.y, sa[1]);
                    sa[2] = fmaf(yp[ss], xv.z, sa[2]);
                    sa[3] = fmaf(yp[ss], xv.w, sa[3]);
                }
            }
        }
        float tmax = fmaxf(fmaxf(sa[0], sa[1]), fmaxf(sa[2], sa[3]));
        #pragma unroll
        for (int ww = 1; ww < 16; ww <<= 1) tmax = fmaxf(tmax, __shfl_xor(tmax, ww, 64));
        const float mnew = fmaxf(m, tmax);
        const float scale = __expf(m - mnew);
        const float p0 = __expf(sa[0] - mnew), p1 = __expf(sa[1] - mnew);
        const float p2 = __expf(sa[2] - mnew), p3 = __expf(sa[3] - mnew);
        float ts = p0 + p1 + p2 + p3;
        #pragma unroll
        for (int ww = 1; ww < 16; ww <<= 1) ts += __shfl_xor(ts, ww, 64);
        l = l * scale + ts; m = mnew;
        #pragma unroll
        for (int ii = 0; ii < 8; ++ii) {
            o[ii].x *= scale; o[ii].y *= scale; o[ii].z *= scale; o[ii].w *= scale;
        }
        *(float4*)&Pl[j][c0] = make_float4(p0, p1, p2, p3);
        for (int ccc = 0; ccc < 8; ++ccc) {
            const int xr = tid >> 5, xq = (tid & 31) * 4;
            const float* xg = x + xbase + (size_t)(xtt * 64 + ccc * 8 + xr) * D_DIM + xq;
            const float4 x0 = *(const float4*)(xg + 0);
            const float4 x1 = *(const float4*)(xg + 128);
            const float4 x2 = *(const float4*)(xg + 256);
            const float4 x3 = *(const float4*)(xg + 384);
            __syncthreads();
            *(float4*)&Xl[xr][xq +   0] = x0; *(float4*)&Xl[xr][xq + 128] = x1;
            *(float4*)&Xl[xr][xq + 256] = x2; *(float4*)&Xl[xr][xq + 384] = x3;
            __syncthreads();
            #pragma unroll
            for (int c = 0; c < 8; ++c) {
                const float pv = Pl[j][ccc * 8 + c];
                #pragma unroll
                for (int ii = 0; ii < 8; ++ii) {
                    const float4 xv = *(const float4*)&Xl[c][tc * 4 + 64 * ii];
                    o[ii].x = fmaf(pv, xv.x, o[ii].x); o[ii].y = fmaf(pv, xv.y, o[ii].y);
                    o[ii].z = fmaf(pv, xv.z, o[ii].z); o[ii].w = fmaf(pv, xv.w, o[ii].w);
                }
            }
        }
    }
    const float inv = 1.0f / l;
    float* og = out + (size_t)(b * LY + jtb * 16 + j) * D_DIM;
    #pragma unroll
    for (int ii = 0; ii < 8; ++ii) {
        float4 v = o[ii];
        v.x *= inv; v.y *= inv; v.z *= inv; v.w *= inv;
        *(float4*)(og + tc * 4 + 64 * ii) = v;
    }
}

// ---------------------------------------------------------------------------
extern "C" void kernel_launch(void* const* d_in, const int* in_sizes, int n_in,
                              void* d_out, int out_size, void* d_ws, size_t ws_size,
                              hipStream_t stream)
{
    const float* x  = (const float*)d_in[0];
    const float* y  = (const float*)d_in[1];
    const float* Wb = (const float*)d_in[2];
    float* out = (float*)d_out;

    const size_t OFF_XFH = 0,         OFF_XFL = 16777216;
    const size_t OFF_YFH = 33554432,  OFF_YFL = 50331648;
    const size_t OFF_XTF = 67108864;
    const size_t OFF_XWH = 83886080,  OFF_XWL = 100663296;
    const size_t OFF_WFH = 117440512, OFF_WFL = 117964800;
    const size_t NEEDED  = 118489088;

    if (ws_size >= NEEDED) {
        char* ws = (char*)d_ws;
        unsigned short* xfh = (unsigned short*)(ws + OFF_XFH);
        unsigned short* xfl = (unsigned short*)(ws + OFF_XFL);
        unsigned short* yfh = (unsigned short*)(ws + OFF_YFH);
        unsigned short* yfl = (unsigned short*)(ws + OFF_YFL);
        unsigned short* xtf = (unsigned short*)(ws + OFF_XTF);
        unsigned short* xwfh = (unsigned short*)(ws + OFF_XWH);
        unsigned short* xwfl = (unsigned short*)(ws + OFF_XWL);
        unsigned short* wfh = (unsigned short*)(ws + OFF_WFH);
        unsigned short* wfl = (unsigned short*)(ws + OFF_WFL);

        prep_k<<<10368, 256, 0, stream>>>(x, y, Wb, xfh, xfl, yfh, yfl, wfh, wfl, xtf);
        dim3 g1(128, 8);
        xw_mfma_k<<<g1, 256, 0, stream>>>(xfh, xfl, wfh, wfl, xwfh, xwfl);
        dim3 g2(64, 8);
        flash3_k<<<g2, 256, 0, stream>>>(yfh, yfl, xwfh, xwfl, xtf, out);
    } else {
        float* xw = (float*)d_ws;
        dim3 g1(NB * LX / 64, D_DIM / 64);
        xw_gemm_fb<<<g1, 256, 0, stream>>>(x, Wb, xw);
        dim3 g2(LY / 16, NB);
        flash_fb<<<g2, 256, 0, stream>>>(x, y, xw, out);
    }
}

// Round 5
// 328.837 us; speedup vs baseline: 1.8992x; 1.1666x over previous
//
#include <hip/hip_runtime.h>
#include <hip/hip_bf16.h>
#include <math.h>

#define D_DIM 512
#define LX 2048
#define LY 2048
#define NB 8

typedef float f32x4 __attribute__((ext_vector_type(4)));
typedef __bf16 bf16x8 __attribute__((ext_vector_type(8)));

__device__ __forceinline__ unsigned short f2bf_rn(float f) {
    unsigned u = __float_as_uint(f);
    unsigned r = (u + 0x7fffu + ((u >> 16) & 1u)) >> 16;
    return (unsigned short)r;
}
__device__ __forceinline__ float bf2f(unsigned short h) {
    return __uint_as_float(((unsigned)h) << 16);
}
__device__ __forceinline__ void async16(void* lds, const void* g) {
    __builtin_amdgcn_global_load_lds(
        (const __attribute__((address_space(1))) void*)g,
        (__attribute__((address_space(3))) void*)lds, 16, 0, 0);
}
__device__ __forceinline__ bf16x8 ldfrag(const char* p) {
    return *(const bf16x8*)p;
}

// ---------------------------------------------------------------------------
// prep_k: fused prologue.
//   blocks [0,4096)    : x  -> xfh/xfl  (frag-order hi/lo)
//   blocks [4096,8192) : y  -> yfh/yfl
//   blocks [8192,8320) : Wb -> wfh/wfl
//   blocks [8320,10368): x  -> xtf (transposed frag-order, bf16 hi only)
// ---------------------------------------------------------------------------
__global__ __launch_bounds__(256) void prep_k(
    const float* __restrict__ x, const float* __restrict__ y,
    const float* __restrict__ Wb,
    unsigned short* __restrict__ xfh, unsigned short* __restrict__ xfl,
    unsigned short* __restrict__ yfh, unsigned short* __restrict__ yfl,
    unsigned short* __restrict__ wfh, unsigned short* __restrict__ wfl,
    unsigned short* __restrict__ xtf)
{
    __shared__ unsigned short T2[64][72];
    const int blk = blockIdx.x, tid = threadIdx.x;

    if (blk < 8320) {
        const float* src; unsigned short *dh, *dl; int base;
        if (blk < 4096)      { src = x;  dh = xfh; dl = xfl; base = blk; }
        else if (blk < 8192) { src = y;  dh = yfh; dl = yfl; base = blk - 4096; }
        else                 { src = Wb; dh = wfh; dl = wfl; base = blk - 8192; }
        int fbid = base * 4 + (tid >> 6);
        int lane = tid & 63;
        int r16 = fbid >> 4, k32 = fbid & 15;
        int row = r16 * 16 + (lane & 15);
        int col = k32 * 32 + (lane >> 4) * 8;
        const float* s = src + (size_t)row * D_DIM + col;
        float4 v0 = *(const float4*)s;
        float4 v1 = *(const float4*)(s + 4);
        float vv[8] = {v0.x, v0.y, v0.z, v0.w, v1.x, v1.y, v1.z, v1.w};
        unsigned hh[4], ll[4];
        #pragma unroll
        for (int k = 0; k < 4; ++k) {
            unsigned short ha = f2bf_rn(vv[2*k]),   hb = f2bf_rn(vv[2*k+1]);
            unsigned short la = f2bf_rn(vv[2*k]   - bf2f(ha));
            unsigned short lb = f2bf_rn(vv[2*k+1] - bf2f(hb));
            hh[k] = (unsigned)ha | ((unsigned)hb << 16);
            ll[k] = (unsigned)la | ((unsigned)lb << 16);
        }
        size_t off = (size_t)fbid * 512 + lane * 8;
        *(uint4*)(dh + off) = make_uint4(hh[0], hh[1], hh[2], hh[3]);
        *(uint4*)(dl + off) = make_uint4(ll[0], ll[1], ll[2], ll[3]);
    } else {
        int idx = blk - 8320;
        int ct = idx & 31, dt = (idx >> 5) & 7, b = idx >> 8;
        const float* xb = x + (size_t)b * LX * D_DIM;
        int rc = tid >> 4;
        int d4 = (tid & 15) * 4;
        #pragma unroll
        for (int i = 0; i < 4; ++i) {
            int cl = rc + i * 16;
            float4 v = *(const float4*)(xb + (size_t)(ct * 64 + cl) * D_DIM + dt * 64 + d4);
            T2[d4 + 0][cl] = f2bf_rn(v.x);
            T2[d4 + 1][cl] = f2bf_rn(v.y);
            T2[d4 + 2][cl] = f2bf_rn(v.z);
            T2[d4 + 3][cl] = f2bf_rn(v.w);
        }
        __syncthreads();
        #pragma unroll
        for (int si = 0; si < 2; ++si) {
            int s = tid + si * 256;
            int fb = s >> 6, lane = s & 63;
            int dd16l = fb >> 1, c32l = fb & 1;
            int ddl = dd16l * 16 + (lane & 15);
            int cl  = c32l * 32 + (lane >> 4) * 8;
            uint4 v = *(const uint4*)&T2[ddl][cl];
            size_t off = ((size_t)((b * 32 + dt * 4 + dd16l) * 64 + (ct * 2 + c32l)) * 64 + lane) * 8;
            *(uint4*)(xtf + off) = v;
        }
    }
}

// ---------------------------------------------------------------------------
// k1: xw = x @ Wb^T, 3-term hi/lo MFMA, single-barrier double-buffered K-loop.
// (unchanged from R4 — works, small share of total time)
// ---------------------------------------------------------------------------
__global__ __launch_bounds__(256, 2) void xw_mfma_k(
    const unsigned short* __restrict__ xfh, const unsigned short* __restrict__ xfl,
    const unsigned short* __restrict__ wfh, const unsigned short* __restrict__ wfl,
    unsigned short* __restrict__ xwfh, unsigned short* __restrict__ xwfl)
{
    __shared__ char smem[49152];
    const int tid = threadIdx.x, lane = tid & 63, w = tid >> 6;
    const int Mt = blockIdx.x, Nt = blockIdx.y;

    f32x4 acc[2][4];
    #pragma unroll
    for (int m = 0; m < 2; ++m)
        #pragma unroll
        for (int n = 0; n < 4; ++n) acc[m][n] = (f32x4){0.f, 0.f, 0.f, 0.f};

    auto stage = [&](int kc, int buf) {
        char* sb = smem + buf * 24576;
        #pragma unroll
        for (int i = 0; i < 4; ++i) {
            int s = w + 4 * i;
            int c16l = s >> 1, h = s & 1;
            size_t fb = ((size_t)(Mt * 8 + c16l)) * 16 + kc;
            const unsigned short* src = (h ? xfl : xfh) + fb * 512 + lane * 8;
            async16(sb + h * 8192 + c16l * 1024 + lane * 16, src);
        }
        #pragma unroll
        for (int i = 0; i < 2; ++i) {
            int s = w + 4 * i;
            int n16l = s >> 1, h = s & 1;
            size_t fb = ((size_t)(Nt * 4 + n16l)) * 16 + kc;
            const unsigned short* src = (h ? wfl : wfh) + fb * 512 + lane * 8;
            async16(sb + 16384 + h * 4096 + n16l * 1024 + lane * 16, src);
        }
    };

    stage(0, 0);
    __syncthreads();
    for (int kc = 0; kc < 16; ++kc) {
        if (kc < 15) stage(kc + 1, (kc + 1) & 1);
        char* sb = smem + (kc & 1) * 24576;
        bf16x8 ah[2], al[2], bh[4], bl[4];
        #pragma unroll
        for (int m = 0; m < 2; ++m) {
            int c16l = w * 2 + m;
            ah[m] = ldfrag(sb + c16l * 1024 + lane * 16);
            al[m] = ldfrag(sb + 8192 + c16l * 1024 + lane * 16);
        }
        #pragma unroll
        for (int n = 0; n < 4; ++n) {
            bh[n] = ldfrag(sb + 16384 + n * 1024 + lane * 16);
            bl[n] = ldfrag(sb + 20480 + n * 1024 + lane * 16);
        }
        #pragma unroll
        for (int m = 0; m < 2; ++m)
            #pragma unroll
            for (int n = 0; n < 4; ++n) {
                acc[m][n] = __builtin_amdgcn_mfma_f32_16x16x32_bf16(ah[m], bh[n], acc[m][n], 0, 0, 0);
                acc[m][n] = __builtin_amdgcn_mfma_f32_16x16x32_bf16(ah[m], bl[n], acc[m][n], 0, 0, 0);
                acc[m][n] = __builtin_amdgcn_mfma_f32_16x16x32_bf16(al[m], bh[n], acc[m][n], 0, 0, 0);
            }
        __syncthreads();
    }

    float* E = (float*)smem;
    const int q = lane >> 4, c15 = lane & 15;
    #pragma unroll
    for (int m = 0; m < 2; ++m)
        #pragma unroll
        for (int n = 0; n < 4; ++n)
            #pragma unroll
            for (int r = 0; r < 4; ++r)
                E[(w * 32 + m * 16 + q * 4 + r) * 68 + n * 16 + c15] = acc[m][n][r];
    __syncthreads();
    #pragma unroll
    for (int i = 0; i < 4; ++i) {
        int s = tid + i * 256;
        int c16l = s >> 7, e32l = (s >> 6) & 1, lp = s & 63;
        int row = c16l * 16 + (lp & 15), col = e32l * 32 + (lp >> 4) * 8;
        const float* sp = E + row * 68 + col;
        unsigned hh[4], ll[4];
        #pragma unroll
        for (int k = 0; k < 4; ++k) {
            float a = sp[2 * k], bq = sp[2 * k + 1];
            unsigned short ha = f2bf_rn(a), hb = f2bf_rn(bq);
            unsigned short la = f2bf_rn(a - bf2f(ha)), lb = f2bf_rn(bq - bf2f(hb));
            hh[k] = (unsigned)ha | ((unsigned)hb << 16);
            ll[k] = (unsigned)la | ((unsigned)lb << 16);
        }
        size_t fb = (size_t)(Mt * 8 + c16l) * 16 + (Nt * 2 + e32l);
        *(uint4*)(xwfh + fb * 512 + lp * 8) = make_uint4(hh[0], hh[1], hh[2], hh[3]);
        *(uint4*)(xwfl + fb * 512 + lp * 8) = make_uint4(ll[0], ll[1], ll[2], ll[3]);
    }
}

// ---------------------------------------------------------------------------
// k2: flash4 — 512 threads (8 waves), j-tile 64, c-tile 256.
// S: wave (jh = w>>2, cw = w&3) computes 32j x 64c (2m x 4n), 3-term hi/lo.
// PV: wave (jh, dq = w&3) computes 32j x 128d.
// LDS: S chunk bufs 2 x 40960 [0,81920) (XW hi 16K | XW lo 16K | Y 8K);
//      PV Xt chunks alias S bufs (32 KB used of each 40 KB slot);
//      Pf 32 KB @81920; red_max/red_sum @114688/115712. Total 116736 B.
// ---------------------------------------------------------------------------
#define SBUF 40960

__global__ __launch_bounds__(512, 2) void flash4_k(
    const unsigned short* __restrict__ yfh, const unsigned short* __restrict__ yfl,
    const unsigned short* __restrict__ xwfh, const unsigned short* __restrict__ xwfl,
    const unsigned short* __restrict__ xtf, float* __restrict__ out)
{
    __shared__ char smem[116736];
    const int tid = threadIdx.x, lane = tid & 63, w = tid >> 6;   // w 0..7
    const int jt = blockIdx.x, b = blockIdx.y;
    const int q = lane >> 4, c15 = lane & 15;
    const int jh = w >> 2;            // 0..1 : j-half (32 rows)
    const int cw = w & 3;             // 0..3 : S c-quarter / PV d-quarter
    unsigned short* Pf = (unsigned short*)(smem + 81920);
    float* red_max = (float*)(smem + 114688);   // [cw][64 rows]
    float* red_sum = (float*)(smem + 115712);

    f32x4 o[2][8];
    #pragma unroll
    for (int m = 0; m < 2; ++m)
        #pragma unroll
        for (int n = 0; n < 8; ++n) o[m][n] = (f32x4){0.f, 0.f, 0.f, 0.f};
    float m_run[2][4], l_run[2][4];
    #pragma unroll
    for (int m = 0; m < 2; ++m)
        #pragma unroll
        for (int r = 0; r < 4; ++r) { m_run[m][r] = -INFINITY; l_run[m][r] = 0.f; }

    // S chunk: XW hi [0,16K) 16x1KB, XW lo [16K,32K), Y hi [32K,36K) 4x1KB, Y lo [36K,40K)
    auto stage_s = [&](int xt, int kc, int buf) {
        char* sb = smem + buf * SBUF;
        #pragma unroll
        for (int i = 0; i < 4; ++i) {                 // XW: 32 segs
            int s = w + 8 * i;
            int c16l = s >> 1, h = s & 1;
            size_t fb = ((size_t)(b * 128 + xt * 16 + c16l)) * 16 + kc;
            const unsigned short* src = (h ? xwfl : xwfh) + fb * 512 + lane * 8;
            async16(sb + h * 16384 + c16l * 1024 + lane * 16, src);
        }
        {                                             // Y: 8 segs, one per wave
            int j16l = w & 3, h = w >> 2;
            size_t fb = ((size_t)(b * 128 + jt * 4 + j16l)) * 16 + kc;
            const unsigned short* src = (h ? yfl : yfh) + fb * 512 + lane * 8;
            async16(sb + 32768 + h * 4096 + j16l * 1024 + lane * 16, src);
        }
    };
    // Xt chunk: 32 dd16 x 1 KB for one c32, into the 32 KB head of S-buf slot.
    auto stage_x = [&](int xt, int cc, int buf) {
        char* xb = smem + buf * SBUF;
        #pragma unroll
        for (int i = 0; i < 4; ++i) {
            int dd16 = w + 8 * i;
            size_t off = (((size_t)(b * 32 + dd16)) * 64 + (xt * 8 + cc)) * 512 + lane * 8;
            async16(xb + dd16 * 1024 + lane * 16, xtf + off);
        }
    };

    for (int xt = 0; xt < 8; ++xt) {
        f32x4 sa[2][4];
        #pragma unroll
        for (int m = 0; m < 2; ++m)
            #pragma unroll
            for (int n = 0; n < 4; ++n) sa[m][n] = (f32x4){0.f, 0.f, 0.f, 0.f};

        // ---- S: K=512 in 16 chunks of 32, dbuf, one barrier per chunk ----
        stage_s(xt, 0, 0);
        __syncthreads();
        for (int kc = 0; kc < 16; ++kc) {
            if (kc < 15) stage_s(xt, kc + 1, (kc + 1) & 1);
            char* sb = smem + (kc & 1) * SBUF;
            bf16x8 ah[2], al[2];
            #pragma unroll
            for (int m = 0; m < 2; ++m) {
                ah[m] = ldfrag(sb + 32768 + (jh * 2 + m) * 1024 + lane * 16);
                al[m] = ldfrag(sb + 36864 + (jh * 2 + m) * 1024 + lane * 16);
            }
            #pragma unroll
            for (int n = 0; n < 4; ++n) {
                int c16l = cw * 4 + n;
                bf16x8 bh = ldfrag(sb + c16l * 1024 + lane * 16);
                bf16x8 bl = ldfrag(sb + 16384 + c16l * 1024 + lane * 16);
                #pragma unroll
                for (int m = 0; m < 2; ++m) {
                    sa[m][n] = __builtin_amdgcn_mfma_f32_16x16x32_bf16(ah[m], bh, sa[m][n], 0, 0, 0);
                    sa[m][n] = __builtin_amdgcn_mfma_f32_16x16x32_bf16(ah[m], bl, sa[m][n], 0, 0, 0);
                    sa[m][n] = __builtin_amdgcn_mfma_f32_16x16x32_bf16(al[m], bh, sa[m][n], 0, 0, 0);
                }
            }
            __syncthreads();
        }

        // ---- online softmax over the 256-c tile ----
        float pmax[2][4];
        #pragma unroll
        for (int m = 0; m < 2; ++m)
            #pragma unroll
            for (int r = 0; r < 4; ++r)
                pmax[m][r] = fmaxf(fmaxf(sa[m][0][r], sa[m][1][r]),
                                   fmaxf(sa[m][2][r], sa[m][3][r]));
        #pragma unroll
        for (int d = 1; d < 16; d <<= 1)
            #pragma unroll
            for (int m = 0; m < 2; ++m)
                #pragma unroll
                for (int r = 0; r < 4; ++r)
                    pmax[m][r] = fmaxf(pmax[m][r], __shfl_xor(pmax[m][r], d, 64));
        if (c15 == 0) {
            #pragma unroll
            for (int m = 0; m < 2; ++m)
                #pragma unroll
                for (int r = 0; r < 4; ++r)
                    red_max[cw * 64 + jh * 32 + m * 16 + q * 4 + r] = pmax[m][r];
        }
        __syncthreads();                              // B1
        stage_x(xt, 0, 0);                            // prefetch Xt c32 #0 (region free)
        float mnew[2][4], alpha[2][4];
        #pragma unroll
        for (int m = 0; m < 2; ++m)
            #pragma unroll
            for (int r = 0; r < 4; ++r) {
                int j = jh * 32 + m * 16 + q * 4 + r;
                float t = fmaxf(fmaxf(red_max[j], red_max[64 + j]),
                                fmaxf(red_max[128 + j], red_max[192 + j]));
                float mn = fmaxf(m_run[m][r], t);
                mnew[m][r] = mn;
                alpha[m][r] = __expf(m_run[m][r] - mn);
                m_run[m][r] = mn;
            }
        float psum[2][4] = {};
        #pragma unroll
        for (int m = 0; m < 2; ++m)
            #pragma unroll
            for (int n = 0; n < 4; ++n)
                #pragma unroll
                for (int r = 0; r < 4; ++r) {
                    float p = __expf(sa[m][n][r] - mnew[m][r]);
                    sa[m][n][r] = p;
                    psum[m][r] += p;
                }
        #pragma unroll
        for (int d = 1; d < 16; d <<= 1)
            #pragma unroll
            for (int m = 0; m < 2; ++m)
                #pragma unroll
                for (int r = 0; r < 4; ++r)
                    psum[m][r] += __shfl_xor(psum[m][r], d, 64);
        if (c15 == 0) {
            #pragma unroll
            for (int m = 0; m < 2; ++m)
                #pragma unroll
                for (int r = 0; r < 4; ++r)
                    red_sum[cw * 64 + jh * 32 + m * 16 + q * 4 + r] = psum[m][r];
        }
        // P -> A-frag layout: block = (jh*2+m)*8 + cw*2 + (n>>1)
        #pragma unroll
        for (int m = 0; m < 2; ++m)
            #pragma unroll
            for (int n = 0; n < 4; ++n)
                #pragma unroll
                for (int r = 0; r < 4; ++r) {
                    int blkP = (jh * 2 + m) * 8 + cw * 2 + (n >> 1);
                    int lp = (q * 4 + r) + 16 * ((n & 1) * 2 + (c15 >> 3));
                    Pf[(blkP * 64 + lp) * 8 + (c15 & 7)] = f2bf_rn(sa[m][n][r]);
                }
        __syncthreads();                              // B2: Pf, red_sum, Xt#0 ready
        #pragma unroll
        for (int m = 0; m < 2; ++m)
            #pragma unroll
            for (int r = 0; r < 4; ++r) {
                int j = jh * 32 + m * 16 + q * 4 + r;
                float ts = red_sum[j] + red_sum[64 + j] + red_sum[128 + j] + red_sum[192 + j];
                l_run[m][r] = l_run[m][r] * alpha[m][r] + ts;
            }
        #pragma unroll
        for (int m = 0; m < 2; ++m)
            #pragma unroll
            for (int n = 0; n < 8; ++n)
                #pragma unroll
                for (int r = 0; r < 4; ++r) o[m][n][r] *= alpha[m][r];

        // ---- PV: 8 c32 chunks, dbuf, one barrier per chunk ----
        for (int cc = 0; cc < 8; ++cc) {
            if (cc < 7) stage_x(xt, cc + 1, (cc + 1) & 1);
            char* xb = smem + (cc & 1) * SBUF;
            bf16x8 pa0 = ldfrag((const char*)Pf + (((jh * 2 + 0) * 8 + cc) * 64 + lane) * 16);
            bf16x8 pa1 = ldfrag((const char*)Pf + (((jh * 2 + 1) * 8 + cc) * 64 + lane) * 16);
            #pragma unroll
            for (int n = 0; n < 8; ++n) {
                bf16x8 xv = ldfrag(xb + (cw * 8 + n) * 1024 + lane * 16);
                o[0][n] = __builtin_amdgcn_mfma_f32_16x16x32_bf16(pa0, xv, o[0][n], 0, 0, 0);
                o[1][n] = __builtin_amdgcn_mfma_f32_16x16x32_bf16(pa1, xv, o[1][n], 0, 0, 0);
            }
            __syncthreads();
        }
    }

    // ---- epilogue ----
    #pragma unroll
    for (int m = 0; m < 2; ++m)
        #pragma unroll
        for (int r = 0; r < 4; ++r) {
            float inv = 1.0f / l_run[m][r];
            int j = jt * 64 + jh * 32 + m * 16 + q * 4 + r;
            #pragma unroll
            for (int n = 0; n < 8; ++n) {
                int dd = cw * 128 + n * 16 + c15;
                out[((size_t)(b * 2048 + j)) * 512 + dd] = o[m][n][r] * inv;
            }
        }
}

// ---------------------------------------------------------------------------
// Fallback fp32 path if ws_size is too small for the fast path.
// ---------------------------------------------------------------------------
__global__ __launch_bounds__(256) void xw_gemm_fb(
    const float* __restrict__ x, const float* __restrict__ Wb, float* __restrict__ xw)
{
    __shared__ float As[16][68];
    __shared__ float Bs[16][68];
    const int tid = threadIdx.x;
    const int bm = blockIdx.x * 64, bn = blockIdx.y * 64;
    const int tm = (tid & 15) * 4, tn = (tid >> 4) * 4;
    const int lrow = tid >> 2, lk = (tid & 3) * 4;
    const float* ag = x  + (size_t)(bm + lrow) * D_DIM + lk;
    const float* bg = Wb + (size_t)(bn + lrow) * D_DIM + lk;
    float acc[4][4] = {};
    for (int kt = 0; kt < D_DIM; kt += 16) {
        const float4 av = *(const float4*)(ag + kt);
        const float4 bv = *(const float4*)(bg + kt);
        __syncthreads();
        As[lk+0][lrow] = av.x; As[lk+1][lrow] = av.y; As[lk+2][lrow] = av.z; As[lk+3][lrow] = av.w;
        Bs[lk+0][lrow] = bv.x; Bs[lk+1][lrow] = bv.y; Bs[lk+2][lrow] = bv.z; Bs[lk+3][lrow] = bv.w;
        __syncthreads();
        #pragma unroll
        for (int k = 0; k < 16; ++k) {
            const float4 a = *(const float4*)&As[k][tm];
            const float4 bq = *(const float4*)&Bs[k][tn];
            const float* ap = (const float*)&a;
            const float* bp = (const float*)&bq;
            #pragma unroll
            for (int i = 0; i < 4; ++i)
                #pragma unroll
                for (int jj = 0; jj < 4; ++jj)
                    acc[i][jj] = fmaf(ap[i], bp[jj], acc[i][jj]);
        }
    }
    #pragma unroll
    for (int i = 0; i < 4; ++i)
        *(float4*)&xw[(size_t)(bm + tm + i) * D_DIM + bn + tn] =
            make_float4(acc[i][0], acc[i][1], acc[i][2], acc[i][3]);
}

__global__ __launch_bounds__(256) void flash_fb(
    const float* __restrict__ x, const float* __restrict__ y,
    const float* __restrict__ xw, float* __restrict__ out)
{
    __shared__ float Yl[16][516];
    __shared__ float XWl[64][68];
    __shared__ float Pl[16][68];
    __shared__ float Xl[8][512];
    const int tid = threadIdx.x, b = blockIdx.y, jtb = blockIdx.x;
    const int j = tid >> 4, tc = tid & 15, c0 = tc * 4;
    {
        const float* yg = y + (size_t)(b * LY + jtb * 16 + j) * D_DIM;
        #pragma unroll
        for (int ii = 0; ii < 8; ++ii)
            *(float4*)&Yl[j][tc * 4 + 64 * ii] = *(const float4*)(yg + tc * 4 + 64 * ii);
    }
    float4 o[8];
    #pragma unroll
    for (int ii = 0; ii < 8; ++ii) o[ii] = make_float4(0.f, 0.f, 0.f, 0.f);
    float m = -INFINITY, l = 0.f;
    const size_t xbase = (size_t)b * LX * D_DIM;
    for (int xtt = 0; xtt < LX / 64; ++xtt) {
        float sa[4] = {0.f, 0.f, 0.f, 0.f};
        for (int kcc = 0; kcc < D_DIM; kcc += 64) {
            const int sc = tid >> 2, skq = (tid & 3) * 4;
            const float* xwg = xw + xbase + (size_t)(xtt * 64 + sc) * D_DIM + kcc + skq;
            const float4 t0 = *(const float4*)(xwg + 0);
            const float4 t1 = *(const float4*)(xwg + 16);
            const float4 t2 = *(const float4*)(xwg + 32);
            const float4 t3 = *(const float4*)(xwg + 48);
            __syncthreads();
            XWl[skq+ 0][sc]=t0.x; XWl[skq+ 1][sc]=t0.y; XWl[skq+ 2][sc]=t0.z; XWl[skq+ 3][sc]=t0.w;
            XWl[skq+16][sc]=t1.x; XWl[skq+17][sc]=t1.y; XWl[skq+18][sc]=t1.z; XWl[skq+19][sc]=t1.w;
            XWl[skq+32][sc]=t2.x; XWl[skq+33][sc]=t2.y; XWl[skq+34][sc]=t2.z; XWl[skq+35][sc]=t2.w;
            XWl[skq+48][sc]=t3.x; XWl[skq+49][sc]=t3.y; XWl[skq+50][sc]=t3.z; XWl[skq+51][sc]=t3.w;
            __syncthreads();
            #pragma unroll
            for (int k4 = 0; k4 < 16; ++k4) {
                const float4 yv = *(const float4*)&Yl[j][kcc + k4 * 4];
                const float* yp = (const float*)&yv;
                #pragma unroll
                for (int ss = 0; ss < 4; ++ss) {
                    const float4 xv = *(const float4*)&XWl[k4 * 4 + ss][c0];
                    sa[0] = fmaf(yp[ss], xv.x, sa[0]);
                    sa[1] = fmaf(yp[ss], xv.y, sa[1]);
                    sa[2] = fmaf(yp[ss], xv.z, sa[2]);
                    sa[3] = fmaf(yp[ss], xv.w, sa[3]);
                }
            }
        }
        float tmax = fmaxf(fmaxf(sa[0], sa[1]), fmaxf(sa[2], sa[3]));
        #pragma unroll
        for (int ww = 1; ww < 16; ww <<= 1) tmax = fmaxf(tmax, __shfl_xor(tmax, ww, 64));
        const float mnew = fmaxf(m, tmax);
        const float scale = __expf(m - mnew);
        const float p0 = __expf(sa[0] - mnew), p1 = __expf(sa[1] - mnew);
        const float p2 = __expf(sa[2] - mnew), p3 = __expf(sa[3] - mnew);
        float ts = p0 + p1 + p2 + p3;
        #pragma unroll
        for (int ww = 1; ww < 16; ww <<= 1) ts += __shfl_xor(ts, ww, 64);
        l = l * scale + ts; m = mnew;
        #pragma unroll
        for (int ii = 0; ii < 8; ++ii) {
            o[ii].x *= scale; o[ii].y *= scale; o[ii].z *= scale; o[ii].w *= scale;
        }
        *(float4*)&Pl[j][c0] = make_float4(p0, p1, p2, p3);
        for (int ccc = 0; ccc < 8; ++ccc) {
            const int xr = tid >> 5, xq = (tid & 31) * 4;
            const float* xg = x + xbase + (size_t)(xtt * 64 + ccc * 8 + xr) * D_DIM + xq;
            const float4 x0 = *(const float4*)(xg + 0);
            const float4 x1 = *(const float4*)(xg + 128);
            const float4 x2 = *(const float4*)(xg + 256);
            const float4 x3 = *(const float4*)(xg + 384);
            __syncthreads();
            *(float4*)&Xl[xr][xq +   0] = x0; *(float4*)&Xl[xr][xq + 128] = x1;
            *(float4*)&Xl[xr][xq + 256] = x2; *(float4*)&Xl[xr][xq + 384] = x3;
            __syncthreads();
            #pragma unroll
            for (int c = 0; c < 8; ++c) {
                const float pv = Pl[j][ccc * 8 + c];
                #pragma unroll
                for (int ii = 0; ii < 8; ++ii) {
                    const float4 xv = *(const float4*)&Xl[c][tc * 4 + 64 * ii];
                    o[ii].x = fmaf(pv, xv.x, o[ii].x); o[ii].y = fmaf(pv, xv.y, o[ii].y);
                    o[ii].z = fmaf(pv, xv.z, o[ii].z); o[ii].w = fmaf(pv, xv.w, o[ii].w);
                }
            }
        }
    }
    const float inv = 1.0f / l;
    float* og = out + (size_t)(b * LY + jtb * 16 + j) * D_DIM;
    #pragma unroll
    for (int ii = 0; ii < 8; ++ii) {
        float4 v = o[ii];
        v.x *= inv; v.y *= inv; v.z *= inv; v.w *= inv;
        *(float4*)(og + tc * 4 + 64 * ii) = v;
    }
}

// ---------------------------------------------------------------------------
extern "C" void kernel_launch(void* const* d_in, const int* in_sizes, int n_in,
                              void* d_out, int out_size, void* d_ws, size_t ws_size,
                              hipStream_t stream)
{
    const float* x  = (const float*)d_in[0];
    const float* y  = (const float*)d_in[1];
    const float* Wb = (const float*)d_in[2];
    float* out = (float*)d_out;

    const size_t OFF_XFH = 0,         OFF_XFL = 16777216;
    const size_t OFF_YFH = 33554432,  OFF_YFL = 50331648;
    const size_t OFF_XTF = 67108864;
    const size_t OFF_XWH = 83886080,  OFF_XWL = 100663296;
    const size_t OFF_WFH = 117440512, OFF_WFL = 117964800;
    const size_t NEEDED  = 118489088;

    if (ws_size >= NEEDED) {
        char* ws = (char*)d_ws;
        unsigned short* xfh = (unsigned short*)(ws + OFF_XFH);
        unsigned short* xfl = (unsigned short*)(ws + OFF_XFL);
        unsigned short* yfh = (unsigned short*)(ws + OFF_YFH);
        unsigned short* yfl = (unsigned short*)(ws + OFF_YFL);
        unsigned short* xtf = (unsigned short*)(ws + OFF_XTF);
        unsigned short* xwfh = (unsigned short*)(ws + OFF_XWH);
        unsigned short* xwfl = (unsigned short*)(ws + OFF_XWL);
        unsigned short* wfh = (unsigned short*)(ws + OFF_WFH);
        unsigned short* wfl = (unsigned short*)(ws + OFF_WFL);

        prep_k<<<10368, 256, 0, stream>>>(x, y, Wb, xfh, xfl, yfh, yfl, wfh, wfl, xtf);
        dim3 g1(128, 8);
        xw_mfma_k<<<g1, 256, 0, stream>>>(xfh, xfl, wfh, wfl, xwfh, xwfl);
        dim3 g2(32, 8);
        flash4_k<<<g2, 512, 0, stream>>>(yfh, yfl, xwfh, xwfl, xtf, out);
    } else {
        float* xw = (float*)d_ws;
        dim3 g1(NB * LX / 64, D_DIM / 64);
        xw_gemm_fb<<<g1, 256, 0, stream>>>(x, Wb, xw);
        dim3 g2(LY / 16, NB);
        flash_fb<<<g2, 256, 0, stream>>>(x, y, xw, out);
    }
}